// Round 1
// baseline (179.766 us; speedup 1.0000x reference)
//
#include <hip/hip_runtime.h>

#define NS_MAX 2048
#define ES_MAX 16384
#define LN_EPS 1e-5f

// ---------------- init: zero mask/deg/counters, seed BFS at current_node ----
__global__ void zero_init_kernel(int* mask, float* deg, int* cnt, const int* curp, int N){
  int i = blockIdx.x*blockDim.x + threadIdx.x;
  int cur = curp[0];
  if (i < N){ mask[i] = (i == cur) ? 1 : 0; deg[i] = 0.0f; }
  if (i == 0){ cnt[0] = 0; cnt[1] = 0; }
}

// ---------------- BFS hop 1: edges with dst == current_node -----------------
__global__ void hop1_kernel(const int* __restrict__ src, const int* __restrict__ dst,
                            int E, const int* curp, int* mask){
  int cur = curp[0];
  int stride = gridDim.x*blockDim.x;
  int i = blockIdx.x*blockDim.x + threadIdx.x;
  if ((E & 3) == 0){
    const int4* d4 = (const int4*)dst;
    int nv = E >> 2;
    for (int v = i; v < nv; v += stride){
      int4 d = d4[v]; int b = v << 2;
      if (d.x == cur) atomicCAS(&mask[src[b+0]], 0, 2);
      if (d.y == cur) atomicCAS(&mask[src[b+1]], 0, 2);
      if (d.z == cur) atomicCAS(&mask[src[b+2]], 0, 2);
      if (d.w == cur) atomicCAS(&mask[src[b+3]], 0, 2);
    }
  } else {
    for (int e = i; e < E; e += stride)
      if (dst[e] == cur) atomicCAS(&mask[src[e]], 0, 2);
  }
}

// ---------------- BFS hop 2: mask[dst] in {1,2} (stable under 0->3 writes) --
__global__ void hop2_kernel(const int* __restrict__ src, const int* __restrict__ dst,
                            int E, int* mask){
  int stride = gridDim.x*blockDim.x;
  int i = blockIdx.x*blockDim.x + threadIdx.x;
  if ((E & 3) == 0){
    const int4* d4 = (const int4*)dst;
    int nv = E >> 2;
    for (int v = i; v < nv; v += stride){
      int4 d = d4[v]; int b = v << 2;
      int m0 = mask[d.x], m1 = mask[d.y], m2 = mask[d.z], m3 = mask[d.w];
      if (m0 == 1 || m0 == 2) atomicCAS(&mask[src[b+0]], 0, 3);
      if (m1 == 1 || m1 == 2) atomicCAS(&mask[src[b+1]], 0, 3);
      if (m2 == 1 || m2 == 2) atomicCAS(&mask[src[b+2]], 0, 3);
      if (m3 == 1 || m3 == 2) atomicCAS(&mask[src[b+3]], 0, 3);
    }
  } else {
    for (int e = i; e < E; e += stride){
      int m = mask[dst[e]];
      if (m == 1 || m == 2) atomicCAS(&mask[src[e]], 0, 3);
    }
  }
}

// ---------------- deg scatter + edge compaction -----------------------------
__device__ __forceinline__ void deg_edge_one(int eidx, int dvert,
                                             const int* __restrict__ src, const int* __restrict__ mask,
                                             float* deg, int* esrc, int* edst, int* cnt){
  int md = mask[dvert];
  if (md){
    int s = src[eidx];
    if (mask[s]){
      atomicAdd(&deg[dvert], 1.0f);
      int idx = atomicAdd(&cnt[1], 1);
      if (idx < ES_MAX){ esrc[idx] = s; edst[idx] = dvert; }
    }
  }
}

__global__ void degcnt_kernel(const int* __restrict__ src, const int* __restrict__ dst,
                              int E, const int* __restrict__ mask,
                              float* deg, int* esrc, int* edst, int* cnt){
  int stride = gridDim.x*blockDim.x;
  int i = blockIdx.x*blockDim.x + threadIdx.x;
  if ((E & 3) == 0){
    const int4* d4 = (const int4*)dst;
    int nv = E >> 2;
    for (int v = i; v < nv; v += stride){
      int4 d = d4[v]; int b = v << 2;
      deg_edge_one(b+0, d.x, src, mask, deg, esrc, edst, cnt);
      deg_edge_one(b+1, d.y, src, mask, deg, esrc, edst, cnt);
      deg_edge_one(b+2, d.z, src, mask, deg, esrc, edst, cnt);
      deg_edge_one(b+3, d.w, src, mask, deg, esrc, edst, cnt);
    }
  } else {
    for (int e = i; e < E; e += stride) deg_edge_one(e, dst[e], src, mask, deg, esrc, edst, cnt);
  }
}

// ---------------- node compaction -------------------------------------------
__global__ void node_compact_kernel(const int* __restrict__ mask, int* lidx, int* nodelist,
                                    int* cnt, int N){
  int v = blockIdx.x*blockDim.x + threadIdx.x;
  if (v < N && mask[v]){
    int l = atomicAdd(&cnt[0], 1);
    if (l < NS_MAX){ nodelist[l] = v; lidx[v] = l; }
  }
}

// ---------------- gather x rows + per-node dis / w_self ---------------------
__global__ void gather_kernel(const float* __restrict__ x, const int* __restrict__ nodelist,
                              const float* __restrict__ deg,
                              float* Xs, float* dis, float* wself, const int* cnt){
  int ncnt = min(cnt[0], NS_MAX);
  int l = blockIdx.x;
  if (l >= ncnt) return;
  int v = nodelist[l];
  int t = threadIdx.x; // 128
  Xs[l*128 + t] = x[(size_t)v*128 + t];
  if (t == 0){
    float dv = deg[v] + 1.0f;     // + self loop (node_mask)
    dis[l]   = rsqrtf(dv);
    wself[l] = 1.0f / dv;
  }
}

// ---------------- per-edge weights (local ids) ------------------------------
__global__ void wedge_kernel(const int* __restrict__ esrc, const int* __restrict__ edst,
                             const int* __restrict__ lidx, const float* __restrict__ dis,
                             int* els, int* eld, float* ew, const int* cnt){
  int ec = min(cnt[1], ES_MAX);
  int i = blockIdx.x*blockDim.x + threadIdx.x;
  if (i < ec){
    int ls = lidx[esrc[i]], ld = lidx[edst[i]];
    els[i] = ls; eld[i] = ld;
    ew[i] = dis[ls]*dis[ld];
  }
}

// ---------------- dense layer: H = Xs @ W ; AGG = H * w_self ----------------
template<int DIN, int DOUT>
__global__ void gemm_kernel(const float* __restrict__ Xs, const float* __restrict__ W,
                            const float* __restrict__ wself,
                            float* H, float* AGG, const int* cnt){
  int ncnt = min(cnt[0], NS_MAX);
  int l = blockIdx.x;
  if (l >= ncnt) return;
  int t = threadIdx.x; // DOUT
  __shared__ float row[DIN];
  for (int k = t; k < DIN; k += DOUT) row[k] = Xs[l*DIN + k];
  __syncthreads();
  float acc = 0.0f;
  #pragma unroll 8
  for (int k = 0; k < DIN; ++k) acc = fmaf(row[k], W[k*DOUT + t], acc);
  H[l*DOUT + t] = acc;
  AGG[l*DOUT + t] = acc * wself[l];
}

// ---------------- edge scatter: AGG[ld] += w * H[ls] ------------------------
template<int DOUT>
__global__ void scatter_kernel(const float* __restrict__ H, float* AGG,
                               const int* __restrict__ els, const int* __restrict__ eld,
                               const float* __restrict__ ew, const int* cnt){
  int ec = min(cnt[1], ES_MAX);
  int t = threadIdx.x;
  for (int i = blockIdx.x; i < ec; i += gridDim.x){
    float w = ew[i];
    atomicAdd(&AGG[eld[i]*DOUT + t], w * H[els[i]*DOUT + t]);
  }
}

// ---------------- bias + relu + layernorm, write into Xs --------------------
template<int DOUT>
__global__ void ln_kernel(const float* __restrict__ AGG, const float* __restrict__ b,
                          const float* __restrict__ g, const float* __restrict__ be,
                          float* Xout, const int* cnt){
  int ncnt = min(cnt[0], NS_MAX);
  int l = blockIdx.x;
  if (l >= ncnt) return;
  int t = threadIdx.x; // DOUT
  float v = AGG[l*DOUT + t] + b[t];
  v = fmaxf(v, 0.0f);
  __shared__ float red[4];
  // mean
  float s = v;
  #pragma unroll
  for (int o = 32; o >= 1; o >>= 1) s += __shfl_xor(s, o);
  float tot;
  if constexpr (DOUT == 128){
    if ((t & 63) == 0) red[t >> 6] = s;
    __syncthreads();
    tot = red[0] + red[1];
  } else {
    tot = s;
  }
  float mu = tot * (1.0f / DOUT);
  float d = v - mu;
  float s2 = d*d;
  #pragma unroll
  for (int o = 32; o >= 1; o >>= 1) s2 += __shfl_xor(s2, o);
  float tot2;
  if constexpr (DOUT == 128){
    if ((t & 63) == 0) red[2 + (t >> 6)] = s2;
    __syncthreads();
    tot2 = red[2] + red[3];
  } else {
    tot2 = s2;
  }
  float var = tot2 * (1.0f / DOUT);
  float y = d * rsqrtf(var + LN_EPS) * g[t] + be[t];
  Xout[l*DOUT + t] = y;
}

// ---------------- mean pool over subgraph nodes -----------------------------
__global__ void pool_kernel(const float* __restrict__ Xs, float* out, const int* cnt){
  int ncnt = min(cnt[0], NS_MAX);
  int tid = threadIdx.x;
  int grp = tid >> 6, t = tid & 63;   // 16 groups x 64 lanes
  float s = 0.0f;
  for (int l = grp; l < ncnt; l += 16) s += Xs[l*64 + t];
  __shared__ float red[16][64];
  red[grp][t] = s;
  __syncthreads();
  if (grp == 0){
    float tot = 0.0f;
    #pragma unroll
    for (int k = 0; k < 16; ++k) tot += red[k][t];
    out[t] = tot / (float)ncnt;
  }
}

extern "C" void kernel_launch(void* const* d_in, const int* in_sizes, int n_in,
                              void* d_out, int out_size, void* d_ws, size_t ws_size,
                              hipStream_t stream) {
  const float* x    = (const float*)d_in[0];
  const int*   ei   = (const int*)d_in[1];
  const int*   curp = (const int*)d_in[2];
  const float* W1 = (const float*)d_in[3];
  const float* b1 = (const float*)d_in[4];
  const float* g1 = (const float*)d_in[5];
  const float* be1= (const float*)d_in[6];
  const float* W2 = (const float*)d_in[7];
  const float* b2 = (const float*)d_in[8];
  const float* g2 = (const float*)d_in[9];
  const float* be2= (const float*)d_in[10];
  const float* W3 = (const float*)d_in[11];
  const float* b3 = (const float*)d_in[12];
  const float* g3 = (const float*)d_in[13];
  const float* be3= (const float*)d_in[14];

  int N = in_sizes[0] / 128;
  int E = in_sizes[1] / 2;
  const int* src = ei;       // edge_index[0]
  const int* dst = ei + E;   // edge_index[1]

  // workspace carve (256B aligned chunks)
  char* p = (char*)d_ws;
  auto carve = [&](size_t bytes) -> void* {
    void* r = (void*)p;
    p += (bytes + 255) & ~(size_t)255;
    return r;
  };
  int*   mask     = (int*)  carve((size_t)N*4);
  float* deg      = (float*)carve((size_t)N*4);
  int*   lidx     = (int*)  carve((size_t)N*4);
  int*   nodelist = (int*)  carve(NS_MAX*4);
  float* dis      = (float*)carve(NS_MAX*4);
  float* wself    = (float*)carve(NS_MAX*4);
  int*   esrc     = (int*)  carve(ES_MAX*4);
  int*   edst     = (int*)  carve(ES_MAX*4);
  int*   els      = (int*)  carve(ES_MAX*4);
  int*   eld      = (int*)  carve(ES_MAX*4);
  float* ew       = (float*)carve(ES_MAX*4);
  int*   cnt      = (int*)  carve(64);
  float* Xs       = (float*)carve((size_t)NS_MAX*128*4);
  float* H        = (float*)carve((size_t)NS_MAX*128*4);
  float* AGG      = (float*)carve((size_t)NS_MAX*128*4);
  (void)ws_size; (void)n_in; (void)out_size;

  int nblk = (N + 255) / 256;
  zero_init_kernel<<<nblk, 256, 0, stream>>>(mask, deg, cnt, curp, N);

  int eblk = 1024;
  hop1_kernel<<<eblk, 256, 0, stream>>>(src, dst, E, curp, mask);
  hop2_kernel<<<eblk, 256, 0, stream>>>(src, dst, E, mask);
  degcnt_kernel<<<eblk, 256, 0, stream>>>(src, dst, E, mask, deg, esrc, edst, cnt);
  node_compact_kernel<<<nblk, 256, 0, stream>>>(mask, lidx, nodelist, cnt, N);
  gather_kernel<<<NS_MAX, 128, 0, stream>>>(x, nodelist, deg, Xs, dis, wself, cnt);
  wedge_kernel<<<(ES_MAX + 255)/256, 256, 0, stream>>>(esrc, edst, lidx, dis, els, eld, ew, cnt);

  // layer 1: 128 -> 128
  gemm_kernel<128,128><<<NS_MAX, 128, 0, stream>>>(Xs, W1, wself, H, AGG, cnt);
  scatter_kernel<128><<<512, 128, 0, stream>>>(H, AGG, els, eld, ew, cnt);
  ln_kernel<128><<<NS_MAX, 128, 0, stream>>>(AGG, b1, g1, be1, Xs, cnt);
  // layer 2: 128 -> 128
  gemm_kernel<128,128><<<NS_MAX, 128, 0, stream>>>(Xs, W2, wself, H, AGG, cnt);
  scatter_kernel<128><<<512, 128, 0, stream>>>(H, AGG, els, eld, ew, cnt);
  ln_kernel<128><<<NS_MAX, 128, 0, stream>>>(AGG, b2, g2, be2, Xs, cnt);
  // layer 3: 128 -> 64
  gemm_kernel<128,64><<<NS_MAX, 64, 0, stream>>>(Xs, W3, wself, H, AGG, cnt);
  scatter_kernel<64><<<512, 64, 0, stream>>>(H, AGG, els, eld, ew, cnt);
  ln_kernel<64><<<NS_MAX, 64, 0, stream>>>(AGG, b3, g3, be3, Xs, cnt);

  pool_kernel<<<1, 1024, 0, stream>>>((const float*)Xs, (float*)d_out, cnt);
}